// Round 1
// baseline (520.865 us; speedup 1.0000x reference)
//
#include <hip/hip_runtime.h>
#include <cmath>

// NTM memory op: address (cosine softmax + interpolate + shift + sharpen),
// read r = w^T memory, write new_memory = memory*(1 - w e^T) + w a^T.
// B=128, N=8192, M=64, fp32. Three kernels, all stream-ordered.

namespace {
constexpr int B = 128;
constexpr int N = 8192;
constexpr int M = 64;
constexpr float F_EPS = 1e-16f;
constexpr float F_COS_EPS = 1e-8f;

constexpr int ROWS = 128;          // rows per block for kernels 1 & 3
constexpr int T2 = 512;            // threads for weight kernel
constexpr int PER = N / T2;        // 16 elements per thread
}

// ---------------------------------------------------------------------------
// Kernel 1: scores[b][n] = beta[b] * cosine(memory[b][n] + eps, k[b] + eps)
// 256 threads = 4 waves; each wave: 4 rows per float4 iteration (64 lanes x
// 16B = 4 rows x 256B). Reduce dot/norm within 16-lane groups.
// ---------------------------------------------------------------------------
__global__ __launch_bounds__(256) void score_kernel(
    const float* __restrict__ memory, const float* __restrict__ k,
    const float* __restrict__ beta, float* __restrict__ scores)
{
    const int b     = blockIdx.x / (N / ROWS);
    const int chunk = blockIdx.x % (N / ROWS);
    const int wave  = threadIdx.x >> 6;
    const int lane  = threadIdx.x & 63;
    const int grp   = lane >> 4;      // row within 4-row pack
    const int m4    = lane & 15;      // float4 column index

    const float4 kv = reinterpret_cast<const float4*>(k + (size_t)b * M)[m4];
    const float4 ke = make_float4(kv.x + F_EPS, kv.y + F_EPS,
                                  kv.z + F_EPS, kv.w + F_EPS);
    float kn2 = ke.x*ke.x + ke.y*ke.y + ke.z*ke.z + ke.w*ke.w;
    #pragma unroll
    for (int m = 1; m <= 8; m <<= 1) kn2 += __shfl_xor(kn2, m, 64);
    const float knorm = sqrtf(kn2);
    const float bb = beta[b];

    const int rows_per_wave = ROWS / 4;                  // 32
    const int row0 = chunk * ROWS + wave * rows_per_wave;

    #pragma unroll 4
    for (int it = 0; it < rows_per_wave; it += 4) {
        const int row = row0 + it + grp;
        const size_t off = ((size_t)b * N + row) * M;
        const float4 mv = reinterpret_cast<const float4*>(memory + off)[m4];
        const float4 me = make_float4(mv.x + F_EPS, mv.y + F_EPS,
                                      mv.z + F_EPS, mv.w + F_EPS);
        float dot = me.x*ke.x + me.y*ke.y + me.z*ke.z + me.w*ke.w;
        float n2  = me.x*me.x + me.y*me.y + me.z*me.z + me.w*me.w;
        #pragma unroll
        for (int m = 1; m <= 8; m <<= 1) {
            dot += __shfl_xor(dot, m, 64);
            n2  += __shfl_xor(n2,  m, 64);
        }
        if (m4 == 0) {
            const float denom = fmaxf(sqrtf(n2) * knorm, F_COS_EPS);
            scores[(size_t)b * N + row] = bb * (dot / denom);
        }
    }
}

// ---------------------------------------------------------------------------
// Kernel 2: one block per batch. softmax(scores) -> interpolate with w_prev ->
// circular 3-tap shift -> pow(gamma) -> renormalize -> w.  Also zeros r.
// ---------------------------------------------------------------------------
__global__ __launch_bounds__(T2) void weight_kernel(
    const float* __restrict__ scores, const float* __restrict__ g,
    const float* __restrict__ s, const float* __restrict__ gamma,
    const float* __restrict__ w_prev, float* __restrict__ w_out,
    float* __restrict__ r_out)
{
    const int b    = blockIdx.x;
    const int tid  = threadIdx.x;
    const int lane = tid & 63;
    const int wave = tid >> 6;

    __shared__ float wg[N];          // 32 KB
    __shared__ float red[T2 / 64];   // 8 waves

    // zero the r accumulator region (consumed by update_kernel's atomics)
    if (tid < M) r_out[(size_t)b * M + tid] = 0.0f;

    const float* sc = scores + (size_t)b * N;

    float loc[PER];
    float mx = -INFINITY;
    #pragma unroll
    for (int i = 0; i < PER; i++) {
        loc[i] = sc[tid + i * T2];
        mx = fmaxf(mx, loc[i]);
    }
    #pragma unroll
    for (int m = 1; m <= 32; m <<= 1) mx = fmaxf(mx, __shfl_xor(mx, m, 64));
    if (lane == 0) red[wave] = mx;
    __syncthreads();
    float bmx = red[0];
    #pragma unroll
    for (int i = 1; i < T2 / 64; i++) bmx = fmaxf(bmx, red[i]);
    __syncthreads();   // red about to be reused

    float lsum = 0.0f;
    #pragma unroll
    for (int i = 0; i < PER; i++) {
        loc[i] = expf(loc[i] - bmx);
        lsum += loc[i];
    }
    #pragma unroll
    for (int m = 1; m <= 32; m <<= 1) lsum += __shfl_xor(lsum, m, 64);
    if (lane == 0) red[wave] = lsum;
    __syncthreads();
    float bsum = 0.0f;
    #pragma unroll
    for (int i = 1; i < T2 / 64 + 1; i++) bsum += red[i - 1];
    const float inv = 1.0f / bsum;

    const float gb = g[b];
    #pragma unroll
    for (int i = 0; i < PER; i++) {
        const int idx = tid + i * T2;
        const float wr = loc[i] * inv;
        wg[idx] = gb * wr + (1.0f - gb) * w_prev[(size_t)b * N + idx];
    }
    __syncthreads();

    const float s0 = s[b * 3 + 0], s1 = s[b * 3 + 1], s2 = s[b * 3 + 2];
    const float gm = gamma[b];
    float pv[PER];
    float lsum2 = 0.0f;
    #pragma unroll
    for (int i = 0; i < PER; i++) {
        const int idx = tid + i * T2;
        const float sh = wg[(idx - 1) & (N - 1)] * s0
                       + wg[idx] * s1
                       + wg[(idx + 1) & (N - 1)] * s2;
        pv[i] = powf(sh, gm);
        lsum2 += pv[i];
    }
    #pragma unroll
    for (int m = 1; m <= 32; m <<= 1) lsum2 += __shfl_xor(lsum2, m, 64);
    __syncthreads();   // red reuse
    if (lane == 0) red[wave] = lsum2;
    __syncthreads();
    float bsum2 = 0.0f;
    #pragma unroll
    for (int i = 0; i < T2 / 64; i++) bsum2 += red[i];
    const float invn = 1.0f / (bsum2 + F_EPS);

    #pragma unroll
    for (int i = 0; i < PER; i++) {
        const int idx = tid + i * T2;
        w_out[(size_t)b * N + idx] = pv[i] * invn;
    }
}

// ---------------------------------------------------------------------------
// Kernel 3: new_memory = memory*(1 - w e^T) + w a^T, fused with
// r[b][m] = sum_n w[b][n] * memory[b][n][m] (block partials + atomicAdd).
// ---------------------------------------------------------------------------
__global__ __launch_bounds__(256) void update_kernel(
    const float* __restrict__ memory, const float* __restrict__ e,
    const float* __restrict__ a, const float* __restrict__ w,
    float* __restrict__ newmem, float* __restrict__ r_out)
{
    const int b     = blockIdx.x / (N / ROWS);
    const int chunk = blockIdx.x % (N / ROWS);
    const int wave  = threadIdx.x >> 6;
    const int lane  = threadIdx.x & 63;
    const int grp   = lane >> 4;
    const int m4    = lane & 15;

    const float4 ev = reinterpret_cast<const float4*>(e + (size_t)b * M)[m4];
    const float4 av = reinterpret_cast<const float4*>(a + (size_t)b * M)[m4];

    const int rows_per_wave = ROWS / 4;
    const int row0 = chunk * ROWS + wave * rows_per_wave;

    float4 acc = make_float4(0.f, 0.f, 0.f, 0.f);

    #pragma unroll 4
    for (int it = 0; it < rows_per_wave; it += 4) {
        const int row = row0 + it + grp;
        const size_t off = ((size_t)b * N + row) * M;
        const float4 mv = reinterpret_cast<const float4*>(memory + off)[m4];
        const float ww = w[(size_t)b * N + row];
        float4 nv;
        nv.x = mv.x * (1.0f - ww * ev.x) + ww * av.x;
        nv.y = mv.y * (1.0f - ww * ev.y) + ww * av.y;
        nv.z = mv.z * (1.0f - ww * ev.z) + ww * av.z;
        nv.w = mv.w * (1.0f - ww * ev.w) + ww * av.w;
        reinterpret_cast<float4*>(newmem + off)[m4] = nv;
        acc.x += ww * mv.x;
        acc.y += ww * mv.y;
        acc.z += ww * mv.z;
        acc.w += ww * mv.w;
    }

    // reduce across the 4 row-groups (lanes differing in bits 4,5)
    #pragma unroll
    for (int m = 16; m <= 32; m <<= 1) {
        acc.x += __shfl_xor(acc.x, m, 64);
        acc.y += __shfl_xor(acc.y, m, 64);
        acc.z += __shfl_xor(acc.z, m, 64);
        acc.w += __shfl_xor(acc.w, m, 64);
    }

    __shared__ float sred[4][M];
    if (grp == 0) {
        sred[wave][m4 * 4 + 0] = acc.x;
        sred[wave][m4 * 4 + 1] = acc.y;
        sred[wave][m4 * 4 + 2] = acc.z;
        sred[wave][m4 * 4 + 3] = acc.w;
    }
    __syncthreads();
    if (threadIdx.x < M) {
        const float v = sred[0][threadIdx.x] + sred[1][threadIdx.x]
                      + sred[2][threadIdx.x] + sred[3][threadIdx.x];
        atomicAdd(&r_out[(size_t)b * M + threadIdx.x], v);
    }
}

// ---------------------------------------------------------------------------
extern "C" void kernel_launch(void* const* d_in, const int* in_sizes, int n_in,
                              void* d_out, int out_size, void* d_ws, size_t ws_size,
                              hipStream_t stream) {
    const float* memory = (const float*)d_in[0];
    const float* k      = (const float*)d_in[1];
    const float* beta   = (const float*)d_in[2];
    const float* g      = (const float*)d_in[3];
    const float* s      = (const float*)d_in[4];
    const float* gamma  = (const float*)d_in[5];
    const float* w_prev = (const float*)d_in[6];
    const float* e      = (const float*)d_in[7];
    const float* a      = (const float*)d_in[8];

    float* out    = (float*)d_out;
    float* w_out  = out;                                  // [B, N]
    float* r_out  = out + (size_t)B * N;                  // [B, M]
    float* newmem = out + (size_t)B * N + (size_t)B * M;  // [B, N, M]

    // Stage scores in the (not-yet-written) new_memory region: consumed by
    // weight_kernel before update_kernel overwrites it. No ws dependence.
    float* scores = newmem;

    const dim3 blk(256);
    const dim3 grid1(B * (N / ROWS));

    score_kernel<<<grid1, blk, 0, stream>>>(memory, k, beta, scores);
    weight_kernel<<<dim3(B), dim3(T2), 0, stream>>>(scores, g, s, gamma,
                                                    w_prev, w_out, r_out);
    update_kernel<<<grid1, blk, 0, stream>>>(memory, e, a, w_out,
                                             newmem, r_out);
}

// Round 2
// 506.963 us; speedup vs baseline: 1.0274x; 1.0274x over previous
//
#include <hip/hip_runtime.h>
#include <cmath>

// NTM memory op: address (cosine softmax + interpolate + shift + sharpen),
// read r = w^T memory, write new_memory = memory*(1 - w e^T) + w a^T.
// B=128, N=8192, M=64, fp32. Three kernels, all stream-ordered.
//
// Traffic plan: memory (256 MiB) is read twice (score, update) with the
// second read expected to hit L3 (256 MiB Infinity Cache); newmem written
// once with nontemporal stores so the streaming write doesn't evict the
// L3-resident memory copy. Scores are staged as p = exp(beta*cos) in the
// not-yet-written newmem region of d_out; per-chunk partial sums of p are
// staged in the r region (B*CHUNKS == B*M floats), consumed then zeroed by
// weight_kernel before update_kernel's atomics accumulate r.

namespace {
constexpr int B = 128;
constexpr int N = 8192;
constexpr int M = 64;
constexpr float F_EPS = 1e-16f;
constexpr float F_COS_EPS = 1e-8f;

constexpr int ROWS = 128;          // rows per block for kernels 1 & 3
constexpr int CHUNKS = N / ROWS;   // 64 chunks per batch
constexpr int T2 = 1024;           // threads for weight kernel
constexpr int PER = N / T2;        // 8 elements per thread
}

typedef float vfloat4 __attribute__((ext_vector_type(4)));

// ---------------------------------------------------------------------------
// Kernel 1: p[b][n] = exp(beta[b] * cosine(memory[b][n]+eps, k[b]+eps))
// (no max-subtraction: |score| <= ~1, exp can't overflow; softmax divides it
// out exactly). Also writes per-chunk partial sums of p into partial[b][chunk].
// 256 threads = 4 waves; each wave: 4 rows per float4 iteration.
// ---------------------------------------------------------------------------
__global__ __launch_bounds__(256) void score_kernel(
    const float* __restrict__ memory, const float* __restrict__ k,
    const float* __restrict__ beta, float* __restrict__ p_out,
    float* __restrict__ partial)
{
    const int b     = blockIdx.x / CHUNKS;
    const int chunk = blockIdx.x % CHUNKS;
    const int wave  = threadIdx.x >> 6;
    const int lane  = threadIdx.x & 63;
    const int grp   = lane >> 4;      // row within 4-row pack
    const int m4    = lane & 15;      // float4 column index

    const float4 kv = reinterpret_cast<const float4*>(k + (size_t)b * M)[m4];
    const float4 ke = make_float4(kv.x + F_EPS, kv.y + F_EPS,
                                  kv.z + F_EPS, kv.w + F_EPS);
    float kn2 = ke.x*ke.x + ke.y*ke.y + ke.z*ke.z + ke.w*ke.w;
    #pragma unroll
    for (int m = 1; m <= 8; m <<= 1) kn2 += __shfl_xor(kn2, m, 64);
    const float knorm = sqrtf(kn2);
    const float bb = beta[b];

    const int rows_per_wave = ROWS / 4;                  // 32
    const int row0 = chunk * ROWS + wave * rows_per_wave;

    float psum = 0.0f;

    #pragma unroll 4
    for (int it = 0; it < rows_per_wave; it += 4) {
        const int row = row0 + it + grp;
        const size_t off = ((size_t)b * N + row) * M;
        const float4 mv = reinterpret_cast<const float4*>(memory + off)[m4];
        const float4 me = make_float4(mv.x + F_EPS, mv.y + F_EPS,
                                      mv.z + F_EPS, mv.w + F_EPS);
        float dot = me.x*ke.x + me.y*ke.y + me.z*ke.z + me.w*ke.w;
        float n2  = me.x*me.x + me.y*me.y + me.z*me.z + me.w*me.w;
        #pragma unroll
        for (int m = 1; m <= 8; m <<= 1) {
            dot += __shfl_xor(dot, m, 64);
            n2  += __shfl_xor(n2,  m, 64);
        }
        if (m4 == 0) {
            const float denom = fmaxf(sqrtf(n2) * knorm, F_COS_EPS);
            const float pe = expf(bb * (dot / denom));
            p_out[(size_t)b * N + row] = pe;
            psum += pe;
        }
    }

    // psum is nonzero only on lanes 0,16,32,48; fold them into lane 0.
    psum += __shfl_xor(psum, 16, 64);
    psum += __shfl_xor(psum, 32, 64);

    __shared__ float ps[4];
    if (lane == 0) ps[wave] = psum;
    __syncthreads();
    if (threadIdx.x == 0)
        partial[b * CHUNKS + chunk] = ps[0] + ps[1] + ps[2] + ps[3];
}

// ---------------------------------------------------------------------------
// Kernel 2: one block (1024 thr) per batch. Normalize p -> softmax weight,
// interpolate with w_prev, circular 3-tap shift, pow(gamma), renormalize.
// Reads then zeroes the r region (which held the softmax partial sums).
// ---------------------------------------------------------------------------
__global__ __launch_bounds__(T2) void weight_kernel(
    const float* __restrict__ p, const float* __restrict__ g,
    const float* __restrict__ s, const float* __restrict__ gamma,
    const float* __restrict__ w_prev, float* __restrict__ w_out,
    float* __restrict__ r_out)
{
    const int b    = blockIdx.x;
    const int tid  = threadIdx.x;
    const int lane = tid & 63;
    const int wave = tid >> 6;

    __shared__ float wg[N];          // 32 KB
    __shared__ float red[T2 / 64];   // 16 waves
    __shared__ float sS;

    // Sum the 64 per-chunk softmax partials (stored in the r region).
    if (tid < 64) {
        float v = r_out[(size_t)b * M + tid];
        #pragma unroll
        for (int m = 1; m <= 32; m <<= 1) v += __shfl_xor(v, m, 64);
        if (tid == 0) sS = v;
    }
    __syncthreads();
    const float invS = 1.0f / sS;

    // Zero the r accumulator region (consumed by update_kernel's atomics).
    if (tid < M) r_out[(size_t)b * M + tid] = 0.0f;

    const float gb = g[b];
    #pragma unroll
    for (int i = 0; i < PER; i++) {
        const int idx = tid + i * T2;
        const float wr = p[(size_t)b * N + idx] * invS;
        wg[idx] = gb * wr + (1.0f - gb) * w_prev[(size_t)b * N + idx];
    }
    __syncthreads();

    const float s0 = s[b * 3 + 0], s1 = s[b * 3 + 1], s2 = s[b * 3 + 2];
    const float gm = gamma[b];
    float pv[PER];
    float lsum = 0.0f;
    #pragma unroll
    for (int i = 0; i < PER; i++) {
        const int idx = tid + i * T2;
        const float sh = wg[(idx - 1) & (N - 1)] * s0
                       + wg[idx] * s1
                       + wg[(idx + 1) & (N - 1)] * s2;
        pv[i] = powf(sh, gm);
        lsum += pv[i];
    }
    #pragma unroll
    for (int m = 1; m <= 32; m <<= 1) lsum += __shfl_xor(lsum, m, 64);
    if (lane == 0) red[wave] = lsum;
    __syncthreads();
    float bsum = 0.0f;
    #pragma unroll
    for (int i = 0; i < T2 / 64; i++) bsum += red[i];
    const float invn = 1.0f / (bsum + F_EPS);

    #pragma unroll
    for (int i = 0; i < PER; i++) {
        const int idx = tid + i * T2;
        w_out[(size_t)b * N + idx] = pv[i] * invn;
    }
}

// ---------------------------------------------------------------------------
// Kernel 3: new_memory = memory*(1 - w e^T) + w a^T (nontemporal stores),
// fused with r[b][m] = sum_n w[b][n]*memory[b][n][m] (block partials +
// one atomicAdd per element per block).
// ---------------------------------------------------------------------------
__global__ __launch_bounds__(256) void update_kernel(
    const float* __restrict__ memory, const float* __restrict__ e,
    const float* __restrict__ a, const float* __restrict__ w,
    float* __restrict__ newmem, float* __restrict__ r_out)
{
    const int b     = blockIdx.x / CHUNKS;
    const int chunk = blockIdx.x % CHUNKS;
    const int wave  = threadIdx.x >> 6;
    const int lane  = threadIdx.x & 63;
    const int grp   = lane >> 4;
    const int m4    = lane & 15;

    const float4 ev = reinterpret_cast<const float4*>(e + (size_t)b * M)[m4];
    const float4 av = reinterpret_cast<const float4*>(a + (size_t)b * M)[m4];

    const int rows_per_wave = ROWS / 4;
    const int row0 = chunk * ROWS + wave * rows_per_wave;

    float4 acc = make_float4(0.f, 0.f, 0.f, 0.f);

    #pragma unroll 4
    for (int it = 0; it < rows_per_wave; it += 4) {
        const int row = row0 + it + grp;
        const size_t off = ((size_t)b * N + row) * M;
        const float4 mv = reinterpret_cast<const float4*>(memory + off)[m4];
        const float ww = w[(size_t)b * N + row];
        vfloat4 nv;
        nv.x = mv.x * (1.0f - ww * ev.x) + ww * av.x;
        nv.y = mv.y * (1.0f - ww * ev.y) + ww * av.y;
        nv.z = mv.z * (1.0f - ww * ev.z) + ww * av.z;
        nv.w = mv.w * (1.0f - ww * ev.w) + ww * av.w;
        __builtin_nontemporal_store(nv, (vfloat4*)(newmem + off) + m4);
        acc.x += ww * mv.x;
        acc.y += ww * mv.y;
        acc.z += ww * mv.z;
        acc.w += ww * mv.w;
    }

    // reduce across the 4 row-groups (lanes differing in bits 4,5)
    #pragma unroll
    for (int m = 16; m <= 32; m <<= 1) {
        acc.x += __shfl_xor(acc.x, m, 64);
        acc.y += __shfl_xor(acc.y, m, 64);
        acc.z += __shfl_xor(acc.z, m, 64);
        acc.w += __shfl_xor(acc.w, m, 64);
    }

    __shared__ float sred[4][M];
    if (grp == 0) {
        sred[wave][m4 * 4 + 0] = acc.x;
        sred[wave][m4 * 4 + 1] = acc.y;
        sred[wave][m4 * 4 + 2] = acc.z;
        sred[wave][m4 * 4 + 3] = acc.w;
    }
    __syncthreads();
    if (threadIdx.x < M) {
        const float v = sred[0][threadIdx.x] + sred[1][threadIdx.x]
                      + sred[2][threadIdx.x] + sred[3][threadIdx.x];
        atomicAdd(&r_out[(size_t)b * M + threadIdx.x], v);
    }
}

// ---------------------------------------------------------------------------
extern "C" void kernel_launch(void* const* d_in, const int* in_sizes, int n_in,
                              void* d_out, int out_size, void* d_ws, size_t ws_size,
                              hipStream_t stream) {
    const float* memory = (const float*)d_in[0];
    const float* k      = (const float*)d_in[1];
    const float* beta   = (const float*)d_in[2];
    const float* g      = (const float*)d_in[3];
    const float* s      = (const float*)d_in[4];
    const float* gamma  = (const float*)d_in[5];
    const float* w_prev = (const float*)d_in[6];
    const float* e      = (const float*)d_in[7];
    const float* a      = (const float*)d_in[8];

    float* out    = (float*)d_out;
    float* w_out  = out;                                  // [B, N]
    float* r_out  = out + (size_t)B * N;                  // [B, M]
    float* newmem = out + (size_t)B * N + (size_t)B * M;  // [B, N, M]

    // p = exp(scores) staged in the not-yet-written new_memory region;
    // softmax partial sums staged in the r region (B*CHUNKS == B*M).
    float* p      = newmem;
    float* partsum = r_out;

    const dim3 blk(256);
    const dim3 grid1(B * CHUNKS);

    score_kernel<<<grid1, blk, 0, stream>>>(memory, k, beta, p, partsum);
    weight_kernel<<<dim3(B), dim3(T2), 0, stream>>>(p, g, s, gamma,
                                                    w_prev, w_out, r_out);
    update_kernel<<<grid1, blk, 0, stream>>>(memory, e, a, w_out,
                                             newmem, r_out);
}